// Round 1
// baseline (377.696 us; speedup 1.0000x reference)
//
#include <hip/hip_runtime.h>
#include <math.h>

// CognitiveRouter: module routing (4) + grouped expert routing (16), combined
// hierarchical probs, top-4 + renorm.  T=32768, D=1536, fp32 in/out.
//
// R6 (R5 post-mortem: timed graph = ~237us harness fills + ~58us kernel.
// Kernel's pole is the LDS read port: 80 wave-uniform weight broadcast
// ds_read_b128 per 16-col chunk per wave, 16 resident waves/CU -> LDS pipe
// ~25-80us competing with the 32us HBM floor).
// Changes vs R5:
//  1. R=2 rows per lane (RPB 64 -> 128): every weight broadcast now feeds
//     8 FMAs instead of 4 -> LDS reads per row of work drop ~1.9x.
//  2. Grid 512 -> 256 blocks (1 block/CU), resident waves/CU 16 -> 8:
//     per-CU LDS issue pressure halves again; prefetch keeps 10 outstanding
//     dwordx4/wave (80 KB in flight/CU) so 2 waves/SIMD still covers HBM
//     latency (need ~9 KB by Little's law).
//  3. Split-K exchange widened to 2 slots/thread (80 KB overlay); waves 0/1
//     each run the verified R5 epilogue for 64 rows.
//  4. Keep: wave-private staging (no in-loop barriers), register prefetch,
//     LSTRIDE=20 (16B-aligned b128), R5's verified output layout/top-k.

#define DD 1536
#define NM 4
#define NE 16
#define NW 20          // 16 expert rows + 4 module rows
#define RPB 128        // rows per block (2 rows per lane)
#define NWAVE 8        // split-K ways
#define NTHR (NWAVE * 64)
#define CPW 192        // cols per wave (DD / 8)
#define CHUNK 16       // cols staged per iteration
#define LSTRIDE 20     // CHUNK + 4: 16B-aligned rows, 2-way-max bank pattern
#define HS_FLOATS (RPB * LSTRIDE)          // 2560 floats
#define W_FLOATS  (NW * LSTRIDE)           // 400 floats
#define WAVE_REG  (HS_FLOATS + W_FLOATS)   // 2960 floats per wave region

typedef float v4f __attribute__((ext_vector_type(4)));

union SharedMem {
    float stage[NWAVE * WAVE_REG];   // 23680 floats = 94.7 KB (K-loop staging)
    float xch[NW * NTHR * 2];        // 20480 floats = 81.9 KB (epilogue)
};

__global__ __launch_bounds__(NTHR)
void router_kernel(const float* __restrict__ hs,
                   const float* __restrict__ Wm,
                   const float* __restrict__ We,
                   float* __restrict__ out,
                   int T)
{
    __shared__ SharedMem sm;          // 94.7 KB -> 1 block/CU (8 waves)
    const int tid  = threadIdx.x;
    const int wv   = tid >> 6;
    const int lane = tid & 63;
    const int rowBlock = blockIdx.x * RPB;
    const int colStart = wv * CPW;

    float acc0[NW], acc1[NW];
#pragma unroll
    for (int e = 0; e < NW; e++) { acc0[e] = 0.f; acc1[e] = 0.f; }

    // hs staging map: 4 lanes cover one row's 16-col chunk; lane ->
    // (row srow+16i, col group scol), i=0..7 covers 128 rows.
    // 4 consecutive lanes = 64 B contiguous global reads.
    const int srow = lane >> 2;          // 0..15
    const int scol = (lane & 3) << 2;    // 0,4,8,12
    const float* hsBase = hs + (size_t)(rowBlock + srow) * DD + colStart + scol;
    float* myHs = &sm.stage[wv * WAVE_REG];
    float* myW  = myHs + HS_FLOATS;

    // weight staging: rows 0..15 -> We (all lanes), rows 16..19 -> Wm (lanes<16)
    const float* weBase = We + (size_t)srow * DD + colStart + scol;
    const float* wmBase = Wm + (size_t)srow * DD + colStart + scol; // lanes<16 only

    // ---- prefetch chunk 0 ----
    v4f hbuf[8], wbuf0, wbuf1;
#pragma unroll
    for (int i = 0; i < 8; i++)
        hbuf[i] = *(const v4f*)(hsBase + (size_t)(i * 16) * DD);
    wbuf0 = *(const v4f*)(weBase);
    if (lane < 16) wbuf1 = *(const v4f*)(wmBase);

    for (int c = 0; c < CPW; c += CHUNK) {
        // ---- commit prefetched tiles to wave-private LDS ----
#pragma unroll
        for (int i = 0; i < 8; i++)
            *(v4f*)&myHs[(srow + i * 16) * LSTRIDE + scol] = hbuf[i];
        *(v4f*)&myW[srow * LSTRIDE + scol] = wbuf0;
        if (lane < 16)
            *(v4f*)&myW[(16 + srow) * LSTRIDE + scol] = wbuf1;

        // ---- prefetch next chunk while computing this one ----
        if (c + CHUNK < CPW) {
            const int cn = c + CHUNK;
#pragma unroll
            for (int i = 0; i < 8; i++)
                hbuf[i] = *(const v4f*)(hsBase + (size_t)(i * 16) * DD + cn);
            wbuf0 = *(const v4f*)(weBase + cn);
            if (lane < 16) wbuf1 = *(const v4f*)(wmBase + cn);
        }

        // ---- compute: 4 g-steps x (2 hs reads + 20 broadcast w reads + 160 FMA)
#pragma unroll
        for (int g = 0; g < 4; g++) {
            v4f h0 = *(const v4f*)&myHs[lane * LSTRIDE + (g << 2)];
            v4f h1 = *(const v4f*)&myHs[(64 + lane) * LSTRIDE + (g << 2)];
#pragma unroll
            for (int e = 0; e < NW; e++) {
                v4f w = *(const v4f*)&myW[e * LSTRIDE + (g << 2)]; // broadcast
                acc0[e] += h0.x * w.x + h0.y * w.y + h0.z * w.z + h0.w * w.w;
                acc1[e] += h1.x * w.x + h1.y * w.y + h1.z * w.z + h1.w * w.w;
            }
        }
        // no barrier: wave-private staging, wave program order suffices
    }

    // ---- split-K partial exchange: xch[e][slot][tid], conflict-free ----
    __syncthreads();   // staging regions dead for ALL waves before overlay
#pragma unroll
    for (int e = 0; e < NW; e++) {
        sm.xch[e * (NTHR * 2) + tid]        = acc0[e];   // rows lane    (0..63)
        sm.xch[e * (NTHR * 2) + NTHR + tid] = acc1[e];   // rows 64+lane
    }
    __syncthreads();

    if (wv < 2) {
        const int half = wv * NTHR;   // wv0 -> acc0 slots, wv1 -> acc1 slots
        float logit[NW];
#pragma unroll
        for (int e = 0; e < NW; e++) {
            float s = 0.f;
#pragma unroll
            for (int w = 0; w < NWAVE; w++)
                s += sm.xch[e * (NTHR * 2) + half + w * 64 + lane];
            logit[e] = s;
        }

        // module softmax over logit[16..19]
        float mmax = logit[16];
#pragma unroll
        for (int m = 1; m < NM; m++) mmax = fmaxf(mmax, logit[16 + m]);
        float mexp[NM], msum = 0.f;
#pragma unroll
        for (int m = 0; m < NM; m++) { mexp[m] = expf(logit[16 + m] - mmax); msum += mexp[m]; }

        // per-module expert softmax, combined probs
        float comb[NE];
#pragma unroll
        for (int m = 0; m < NM; m++) {
            float mprob = mexp[m] / msum;
            float emax = logit[m * 4];
#pragma unroll
            for (int j = 1; j < 4; j++) emax = fmaxf(emax, logit[m * 4 + j]);
            float ee[4], esum = 0.f;
#pragma unroll
            for (int j = 0; j < 4; j++) { ee[j] = expf(logit[m * 4 + j] - emax); esum += ee[j]; }
            float scale = mprob / esum;
#pragma unroll
            for (int j = 0; j < 4; j++) comb[m * 4 + j] = ee[j] * scale;
        }

        const int row = rowBlock + wv * 64 + lane;
        float4* cw = (float4*)(out + (size_t)row * 16);
        cw[0] = make_float4(comb[0],  comb[1],  comb[2],  comb[3]);
        cw[1] = make_float4(comb[4],  comb[5],  comb[6],  comb[7]);
        cw[2] = make_float4(comb[8],  comb[9],  comb[10], comb[11]);
        cw[3] = make_float4(comb[12], comb[13], comb[14], comb[15]);

        // top-4, descending, strict > so lowest index wins ties (lax.top_k)
        float tv[4]; int ti[4];
        unsigned mask = 0;
#pragma unroll
        for (int k = 0; k < 4; k++) {
            float best = -1.f; int bi = 0;
#pragma unroll
            for (int i = 0; i < NE; i++) {
                bool avail = !((mask >> i) & 1u);
                if (avail && comb[i] > best) { best = comb[i]; bi = i; }
            }
            tv[k] = best; ti[k] = bi; mask |= 1u << bi;
        }
        float s = tv[0] + tv[1] + tv[2] + tv[3] + 1e-8f;

        const size_t wOff = (size_t)T * 16;          // top_k_weights region
        const size_t iOff = (size_t)T * 20;          // top_k_indices region
        float4* ww = (float4*)(out + wOff + (size_t)row * 4);
        *ww = make_float4(tv[0] / s, tv[1] / s, tv[2] / s, tv[3] / s);
        float4* iw = (float4*)(out + iOff + (size_t)row * 4);
        *iw = make_float4((float)ti[0], (float)ti[1], (float)ti[2], (float)ti[3]);
    }
}

extern "C" void kernel_launch(void* const* d_in, const int* in_sizes, int n_in,
                              void* d_out, int out_size, void* d_ws, size_t ws_size,
                              hipStream_t stream)
{
    const float* hs = (const float*)d_in[0];   // (T, 1536)
    const float* Wm = (const float*)d_in[1];   // (4, 1536)
    const float* We = (const float*)d_in[2];   // (16, 1536)
    float* out = (float*)d_out;
    const int T = in_sizes[0] / DD;            // 32768
    router_kernel<<<T / RPB, NTHR, 0, stream>>>(hs, Wm, We, out, T);
}

// Round 2
// 362.259 us; speedup vs baseline: 1.0426x; 1.0426x over previous
//
#include <hip/hip_runtime.h>
#include <math.h>

// CognitiveRouter: module routing (4) + grouped expert routing (16), combined
// hierarchical probs, top-4 + renorm.  T=32768, D=1536, fp32 in/out.
//
// R7 (R6 post-mortem: WRITE_SIZE=180MB scratch spill-through -- hbuf[8]
// prefetch + 40 accs blew the register budget; FETCH grew to 249MB; 1.8M
// LDS bank conflicts from the unpadded-ish (64+lane)*20 read. 188us.)
// Changes vs R6:
//  1. Weights via SCALAR loads (s_load_dwordx4): colStart passed through
//     readfirstlane -> weight addresses provably wave-uniform; We/Wm are
//     unclobbered const __restrict__ -> backend emits SMEM loads into SGPRs.
//     Deletes ALL 80 weight broadcast ds_read_b128 per chunk per wave (the
//     R5 LDS-port pole) and uses zero VGPRs for weights.
//  2. hs staged with global_load_lds (16B/lane, lane-linear LDS dest): no
//     hbuf registers -> no spill. Bank conflicts on the compute read fixed
//     by PRE-SWIZZLING the per-lane global source column (grp ^= (row>>1)&3)
//     and XOR-ing the same on the read: 64 lanes spread over all 8 b128
//     bank-groups (port-minimum 8 phases, zero counted conflicts).
//  3. Single-buffered DMA, per-chunk s_waitcnt vmcnt(0) (wave-private region,
//     no barriers); lgkmcnt(0) fence before each DMA issue so async LDS
//     writes can't land under a still-pending ds_read (rule-18 analog).
//  4. Keep: R=2 rows/lane (RPB=128, grid=256 = 1 block/CU), split-K 8,
//     R6's verified epilogue/output layout/top-k.

#define DD 1536
#define NM 4
#define NE 16
#define NW 20          // 16 expert rows + 4 module rows
#define RPB 128        // rows per block (2 rows per lane)
#define NWAVE 8        // split-K ways
#define NTHR (NWAVE * 64)
#define CPW 192        // cols per wave (DD / 8)
#define CHUNK 16       // cols staged per iteration
#define HS_FLOATS (RPB * CHUNK)   // 2048 floats per wave (lane-linear, swizzled)

typedef float v4f __attribute__((ext_vector_type(4)));

union SharedMem {
    float stage[NWAVE * HS_FLOATS];  // 16384 floats = 64 KB (K-loop staging)
    float xch[NW * NTHR * 2];        // 20480 floats = 80 KB (epilogue)
};

__global__ __launch_bounds__(NTHR)
void router_kernel(const float* __restrict__ hs,
                   const float* __restrict__ Wm,
                   const float* __restrict__ We,
                   float* __restrict__ out,
                   int T)
{
    __shared__ SharedMem sm;          // 80 KB union
    const int tid  = threadIdx.x;
    const int wv   = tid >> 6;
    const int lane = tid & 63;
    const int rowBlock = blockIdx.x * RPB;
    // Wave-uniform column base, forced into an SGPR so weight loads below
    // have provably-uniform addresses -> s_load (SMEM) path.
    const int colStart = __builtin_amdgcn_readfirstlane(wv * CPW);

    float acc0[NW], acc1[NW];
#pragma unroll
    for (int e = 0; e < NW; e++) { acc0[e] = 0.f; acc1[e] = 0.f; }

    // ---- hs DMA staging map (global_load_lds, 16B per lane) ----
    // Instr i writes LDS floats [i*256, i*256+256): lane l -> i*256 + l*4.
    // That position (row = i*16 + (l>>2), grp p = l&3) must hold global
    // col-group p ^ sw(row), sw(row) = (row>>1)&3  (swizzle for bank spread).
    const int srow = lane >> 2;            // 0..15
    const int p    = lane & 3;             // col-group slot in LDS
    const int sw   = (lane >> 3) & 3;      // == (srow>>1)&3 == (row>>1)&3
    const int gcol = ((p ^ sw) << 2);      // swizzled global col offset
    const float* dmaBase = hs + (size_t)(rowBlock + srow) * DD + colStart + gcol;

    const int myHsOff = __builtin_amdgcn_readfirstlane(wv * HS_FLOATS);
    const float* WeBase = We + colStart;   // uniform
    const float* WmBase = Wm + colStart;   // uniform
    const int rsw = ((lane >> 1) & 3);     // read-side swizzle key (row=lane, 64+lane)

    for (int c = 0; c < CPW; c += CHUNK) {
        // All ds_reads of the previous chunk must be complete before the
        // async DMA may overwrite the region (DMA arrival is not ordered
        // with the wave's LDS pipe).
        asm volatile("s_waitcnt lgkmcnt(0)" ::: "memory");
#pragma unroll
        for (int i = 0; i < 8; i++) {
            const float* src = dmaBase + (size_t)(i * 16) * DD + c;
            __builtin_amdgcn_global_load_lds(
                (const __attribute__((address_space(1))) void*)src,
                (__attribute__((address_space(3))) void*)&sm.stage[myHsOff + i * 256],
                16, 0, 0);
        }
        asm volatile("s_waitcnt vmcnt(0)" ::: "memory");

        // ---- compute: 4 g-steps x (2 swizzled hs reads + 20 SGPR weight
        //      quads + 160 FMA). Weights come from SMEM, not LDS. ----
#pragma unroll
        for (int g = 0; g < 4; g++) {
            const int sg = ((g ^ rsw) << 2);
            v4f h0 = *(const v4f*)&sm.stage[myHsOff + (lane << 4) + sg];
            v4f h1 = *(const v4f*)&sm.stage[myHsOff + 1024 + (lane << 4) + sg];
#pragma unroll
            for (int e = 0; e < NE; e++) {
                v4f w = *(const v4f*)(WeBase + e * DD + c + (g << 2)); // s_load
                acc0[e] += h0.x * w.x + h0.y * w.y + h0.z * w.z + h0.w * w.w;
                acc1[e] += h1.x * w.x + h1.y * w.y + h1.z * w.z + h1.w * w.w;
            }
#pragma unroll
            for (int m = 0; m < NM; m++) {
                v4f w = *(const v4f*)(WmBase + m * DD + c + (g << 2)); // s_load
                acc0[16 + m] += h0.x * w.x + h0.y * w.y + h0.z * w.z + h0.w * w.w;
                acc1[16 + m] += h1.x * w.x + h1.y * w.y + h1.z * w.z + h1.w * w.w;
            }
        }
        // no barrier: wave-private staging, wave program order suffices
    }

    // ---- split-K partial exchange: xch[e][slot][tid], conflict-free ----
    __syncthreads();   // staging region dead for ALL waves before overlay
#pragma unroll
    for (int e = 0; e < NW; e++) {
        sm.xch[e * (NTHR * 2) + tid]        = acc0[e];   // rows lane    (0..63)
        sm.xch[e * (NTHR * 2) + NTHR + tid] = acc1[e];   // rows 64+lane
    }
    __syncthreads();

    if (wv < 2) {
        const int half = wv * NTHR;   // wv0 -> acc0 slots, wv1 -> acc1 slots
        float logit[NW];
#pragma unroll
        for (int e = 0; e < NW; e++) {
            float s = 0.f;
#pragma unroll
            for (int w = 0; w < NWAVE; w++)
                s += sm.xch[e * (NTHR * 2) + half + w * 64 + lane];
            logit[e] = s;
        }

        // module softmax over logit[16..19]
        float mmax = logit[16];
#pragma unroll
        for (int m = 1; m < NM; m++) mmax = fmaxf(mmax, logit[16 + m]);
        float mexp[NM], msum = 0.f;
#pragma unroll
        for (int m = 0; m < NM; m++) { mexp[m] = expf(logit[16 + m] - mmax); msum += mexp[m]; }

        // per-module expert softmax, combined probs
        float comb[NE];
#pragma unroll
        for (int m = 0; m < NM; m++) {
            float mprob = mexp[m] / msum;
            float emax = logit[m * 4];
#pragma unroll
            for (int j = 1; j < 4; j++) emax = fmaxf(emax, logit[m * 4 + j]);
            float ee[4], esum = 0.f;
#pragma unroll
            for (int j = 0; j < 4; j++) { ee[j] = expf(logit[m * 4 + j] - emax); esum += ee[j]; }
            float scale = mprob / esum;
#pragma unroll
            for (int j = 0; j < 4; j++) comb[m * 4 + j] = ee[j] * scale;
        }

        const int row = rowBlock + wv * 64 + lane;
        float4* cw = (float4*)(out + (size_t)row * 16);
        cw[0] = make_float4(comb[0],  comb[1],  comb[2],  comb[3]);
        cw[1] = make_float4(comb[4],  comb[5],  comb[6],  comb[7]);
        cw[2] = make_float4(comb[8],  comb[9],  comb[10], comb[11]);
        cw[3] = make_float4(comb[12], comb[13], comb[14], comb[15]);

        // top-4, descending, strict > so lowest index wins ties (lax.top_k)
        float tv[4]; int ti[4];
        unsigned mask = 0;
#pragma unroll
        for (int k = 0; k < 4; k++) {
            float best = -1.f; int bi = 0;
#pragma unroll
            for (int i = 0; i < NE; i++) {
                bool avail = !((mask >> i) & 1u);
                if (avail && comb[i] > best) { best = comb[i]; bi = i; }
            }
            tv[k] = best; ti[k] = bi; mask |= 1u << bi;
        }
        float s = tv[0] + tv[1] + tv[2] + tv[3] + 1e-8f;

        const size_t wOff = (size_t)T * 16;          // top_k_weights region
        const size_t iOff = (size_t)T * 20;          // top_k_indices region
        float4* ww = (float4*)(out + wOff + (size_t)row * 4);
        *ww = make_float4(tv[0] / s, tv[1] / s, tv[2] / s, tv[3] / s);
        float4* iw = (float4*)(out + iOff + (size_t)row * 4);
        *iw = make_float4((float)ti[0], (float)ti[1], (float)ti[2], (float)ti[3]);
    }
}

extern "C" void kernel_launch(void* const* d_in, const int* in_sizes, int n_in,
                              void* d_out, int out_size, void* d_ws, size_t ws_size,
                              hipStream_t stream)
{
    const float* hs = (const float*)d_in[0];   // (T, 1536)
    const float* Wm = (const float*)d_in[1];   // (4, 1536)
    const float* We = (const float*)d_in[2];   // (16, 1536)
    float* out = (float*)d_out;
    const int T = in_sizes[0] / DD;            // 32768
    router_kernel<<<T / RPB, NTHR, 0, stream>>>(hs, Wm, We, out, T);
}

// Round 3
// 292.244 us; speedup vs baseline: 1.2924x; 1.2396x over previous
//
#include <hip/hip_runtime.h>
#include <math.h>

// CognitiveRouter: module routing (4) + grouped expert routing (16), combined
// hierarchical probs, top-4 + renorm.  T=32768, D=1536, fp32 in/out.
//
// R8 (R7 post-mortem: 169us, hbm 884 GB/s (11%), latency-serialized --
// per-chunk vmcnt(0) drain exposed full HBM latency 12x/wave with 2
// waves/SIMD; "scalar" weight loads couldn't fit SGPR budget and re-issued
// per use; 4.7M bank conflicts from the failed swizzle.)
// Restructure -- skinny GEMM (32768x1536 @ 1536x20), floor = stream hs once:
//  1. hs: global->VGPR direct, NO LDS staging, NO DMA, NO vmcnt drains.
//     Lane q=lane&15 owns cols q*4+64j of 2 rows (g=lane>>4, g+4);
//     16-lane groups read 256B contiguous; depth-4 named-reg prefetch.
//  2. Weights: ALL 20x1536 floats staged to LDS once (122,880 B), layout
//     wl[j][e][64] so e-offsets are small immediates. Read = 16 consecutive
//     16B groups x4-way same-address broadcast = 2-way bank dup -> free.
//     One ds_read_b128 feeds 8 FMAs; zero re-staging for rest of kernel.
//  3. Split-K replaced by in-register __shfl_xor butterfly (1,2,4,8) over
//     the 16 col-lanes; epilogue = R6's verified math, run by lanes q<2
//     (q==0 -> row g, q==1 -> row g+4). No union, one __syncthreads total.
//  4. Grid 256 = 1 block/CU (LDS-capped), 2 row-passes of 64 rows.

#define DD 1536
#define NM 4
#define NE 16
#define NW 20          // 16 expert rows + 4 module rows
#define RPB 128        // rows per block
#define NTHR 512
#define NJ 24          // DD / 64 column windows
#define WLDS_F (NJ * NW * 64)   // 30720 floats = 122880 B

typedef float v4f __attribute__((ext_vector_type(4)));

__global__ __launch_bounds__(NTHR)
void router_kernel(const float* __restrict__ hs,
                   const float* __restrict__ Wm,
                   const float* __restrict__ We,
                   float* __restrict__ out,
                   int T)
{
    __shared__ __align__(16) float wl[WLDS_F];   // weights only, read-only after stage
    const int tid  = threadIdx.x;
    const int wv   = tid >> 6;
    const int lane = tid & 63;
    const int q    = lane & 15;       // col-group lane within 64-col window
    const int g    = lane >> 4;       // row sub-group 0..3
    const int rowBlock = blockIdx.x * RPB;

    // ---- stage ALL weights to LDS once: wl[j][e][qcol], off=j*1280+e*64+qcol
    // 30720 floats = 512 threads x 15 v4, coalesced, distinct, exact cover.
#pragma unroll
    for (int i = 0; i < 15; i++) {
        const int off  = tid * 4 + i * 2048;
        const int j    = off / 1280;
        const int rem  = off - j * 1280;
        const int e    = rem >> 6;
        const int qcol = rem & 63;
        const int col  = j * 64 + qcol;
        v4f w = (e < NE) ? *(const v4f*)(We + (size_t)e * DD + col)
                         : *(const v4f*)(Wm + (size_t)(e - NE) * DD + col);
        *(v4f*)&wl[off] = w;
    }
    __syncthreads();

#pragma unroll 1
    for (int p = 0; p < 2; p++) {
        const int rA = rowBlock + p * 64 + wv * 8 + g;    // rows rA and rA+4
        const float* hsA = hs + (size_t)rA * DD + q * 4;
        const float* hsB = hsA + 4 * DD;

        float accA[NW], accB[NW];
#pragma unroll
        for (int e = 0; e < NW; e++) { accA[e] = 0.f; accB[e] = 0.f; }

        // depth-4 register prefetch (named bufs, static indexing)
        v4f a0 = *(const v4f*)(hsA);
        v4f b0 = *(const v4f*)(hsB);
        v4f a1 = *(const v4f*)(hsA + 64);
        v4f b1 = *(const v4f*)(hsB + 64);

#pragma unroll 1
        for (int j = 0; j < NJ; j += 2) {
            v4f a2, b2, a3, b3;
            if (j + 2 < NJ) {
                a2 = *(const v4f*)(hsA + (size_t)(j + 2) * 64);
                b2 = *(const v4f*)(hsB + (size_t)(j + 2) * 64);
                a3 = *(const v4f*)(hsA + (size_t)(j + 3) * 64);
                b3 = *(const v4f*)(hsB + (size_t)(j + 3) * 64);
            }
            // step j: weights wl[j][e][q*4..+3], imm offsets e*256B
            {
                const float* wb = &wl[j * 1280 + q * 4];
#pragma unroll
                for (int e = 0; e < NW; e++) {
                    v4f w = *(const v4f*)(wb + e * 64);
                    accA[e] = fmaf(a0.x, w.x, accA[e]);
                    accA[e] = fmaf(a0.y, w.y, accA[e]);
                    accA[e] = fmaf(a0.z, w.z, accA[e]);
                    accA[e] = fmaf(a0.w, w.w, accA[e]);
                    accB[e] = fmaf(b0.x, w.x, accB[e]);
                    accB[e] = fmaf(b0.y, w.y, accB[e]);
                    accB[e] = fmaf(b0.z, w.z, accB[e]);
                    accB[e] = fmaf(b0.w, w.w, accB[e]);
                }
            }
            // step j+1
            {
                const float* wb = &wl[(j + 1) * 1280 + q * 4];
#pragma unroll
                for (int e = 0; e < NW; e++) {
                    v4f w = *(const v4f*)(wb + e * 64);
                    accA[e] = fmaf(a1.x, w.x, accA[e]);
                    accA[e] = fmaf(a1.y, w.y, accA[e]);
                    accA[e] = fmaf(a1.z, w.z, accA[e]);
                    accA[e] = fmaf(a1.w, w.w, accA[e]);
                    accB[e] = fmaf(b1.x, w.x, accB[e]);
                    accB[e] = fmaf(b1.y, w.y, accB[e]);
                    accB[e] = fmaf(b1.z, w.z, accB[e]);
                    accB[e] = fmaf(b1.w, w.w, accB[e]);
                }
            }
            a0 = a2; b0 = b2; a1 = a3; b1 = b3;
        }

        // ---- in-register split-col reduction over the 16 q-lanes ----
#pragma unroll
        for (int e = 0; e < NW; e++) {
            accA[e] += __shfl_xor(accA[e], 1);
            accA[e] += __shfl_xor(accA[e], 2);
            accA[e] += __shfl_xor(accA[e], 4);
            accA[e] += __shfl_xor(accA[e], 8);
            accB[e] += __shfl_xor(accB[e], 1);
            accB[e] += __shfl_xor(accB[e], 2);
            accB[e] += __shfl_xor(accB[e], 4);
            accB[e] += __shfl_xor(accB[e], 8);
        }

        // ---- epilogue (verified R6 math): q==0 -> row rA, q==1 -> row rA+4
        if (q < 2) {
            float logit[NW];
#pragma unroll
            for (int e = 0; e < NW; e++) logit[e] = q ? accB[e] : accA[e];
            const int row = rA + (q ? 4 : 0);

            // module softmax over logit[16..19]
            float mmax = logit[16];
#pragma unroll
            for (int m = 1; m < NM; m++) mmax = fmaxf(mmax, logit[16 + m]);
            float mexp[NM], msum = 0.f;
#pragma unroll
            for (int m = 0; m < NM; m++) { mexp[m] = expf(logit[16 + m] - mmax); msum += mexp[m]; }

            // per-module expert softmax, combined probs
            float comb[NE];
#pragma unroll
            for (int m = 0; m < NM; m++) {
                float mprob = mexp[m] / msum;
                float emax = logit[m * 4];
#pragma unroll
                for (int jj = 1; jj < 4; jj++) emax = fmaxf(emax, logit[m * 4 + jj]);
                float ee[4], esum = 0.f;
#pragma unroll
                for (int jj = 0; jj < 4; jj++) { ee[jj] = expf(logit[m * 4 + jj] - emax); esum += ee[jj]; }
                float scale = mprob / esum;
#pragma unroll
                for (int jj = 0; jj < 4; jj++) comb[m * 4 + jj] = ee[jj] * scale;
            }

            float4* cw = (float4*)(out + (size_t)row * 16);
            cw[0] = make_float4(comb[0],  comb[1],  comb[2],  comb[3]);
            cw[1] = make_float4(comb[4],  comb[5],  comb[6],  comb[7]);
            cw[2] = make_float4(comb[8],  comb[9],  comb[10], comb[11]);
            cw[3] = make_float4(comb[12], comb[13], comb[14], comb[15]);

            // top-4, descending, strict > so lowest index wins ties (lax.top_k)
            float tv[4]; int ti[4];
            unsigned mask = 0;
#pragma unroll
            for (int k = 0; k < 4; k++) {
                float best = -1.f; int bi = 0;
#pragma unroll
                for (int i = 0; i < NE; i++) {
                    bool avail = !((mask >> i) & 1u);
                    if (avail && comb[i] > best) { best = comb[i]; bi = i; }
                }
                tv[k] = best; ti[k] = bi; mask |= 1u << bi;
            }
            float s = tv[0] + tv[1] + tv[2] + tv[3] + 1e-8f;

            const size_t wOff = (size_t)T * 16;          // top_k_weights region
            const size_t iOff = (size_t)T * 20;          // top_k_indices region
            float4* ww = (float4*)(out + wOff + (size_t)row * 4);
            *ww = make_float4(tv[0] / s, tv[1] / s, tv[2] / s, tv[3] / s);
            float4* iw = (float4*)(out + iOff + (size_t)row * 4);
            *iw = make_float4((float)ti[0], (float)ti[1], (float)ti[2], (float)ti[3]);
        }
    }
}

extern "C" void kernel_launch(void* const* d_in, const int* in_sizes, int n_in,
                              void* d_out, int out_size, void* d_ws, size_t ws_size,
                              hipStream_t stream)
{
    const float* hs = (const float*)d_in[0];   // (T, 1536)
    const float* Wm = (const float*)d_in[1];   // (4, 1536)
    const float* We = (const float*)d_in[2];   // (16, 1536)
    float* out = (float*)d_out;
    const int T = in_sizes[0] / DD;            // 32768
    router_kernel<<<T / RPB, NTHR, 0, stream>>>(hs, Wm, We, out, T);
}